// Round 1
// baseline (417.023 us; speedup 1.0000x reference)
//
#include <hip/hip_runtime.h>
#include <math.h>

// Problem constants (fixed by the reference setup_inputs)
#define NN 8192
#define SS 32
#define DD 32
#define KK 1024
#define OUT_ELEMS ((size_t)NN * SS * DD)   // 8388608; loss scalar lives at out[OUT_ELEMS]

// loss = S * (1 + BETA) * sum_sq / (N*S*D)
#define LOSS_SCALE (32.0f * 1.001f / 8388608.0f)

__global__ void vq_zero_loss(float* __restrict__ out) {
    out[OUT_ELEMS] = 0.0f;
}

// One thread per (n, s). s is wave-uniform so W-row loads in the k-loop are
// scalar (s_load) and the inner loop is pure v_fmac with one SGPR operand.
__global__ __launch_bounds__(256) void vq_main(const float* __restrict__ z,
                                               const float* __restrict__ W,
                                               float* __restrict__ out) {
    __shared__ float lds_w2[KK];
    __shared__ float lds_red[4];

    const int s     = blockIdx.x & (SS - 1);        // wave-uniform
    const int nbase = (blockIdx.x >> 5) * 256;
    const int tid   = threadIdx.x;
    const float* __restrict__ Ws = W + (size_t)s * KK * DD;

    // Precompute ||W[s,k]||^2 into LDS (once per block; 4 k per thread).
    #pragma unroll
    for (int j = 0; j < 4; ++j) {
        const int k = tid + j * 256;
        const float* wr = Ws + (size_t)k * DD;
        float acc = 0.0f;
        #pragma unroll
        for (int d = 0; d < DD; ++d) acc = fmaf(wr[d], wr[d], acc);
        lds_w2[k] = acc;
    }
    __syncthreads();

    const int n = nbase + tid;

    // z row -> VGPRs (float4 loads; 128 B per lane, each line fully consumed)
    float zr[DD];
    const float* zp = z + (size_t)n * (SS * DD) + (size_t)s * DD;
    #pragma unroll
    for (int c = 0; c < DD / 4; ++c) {
        float4 v = reinterpret_cast<const float4*>(zp)[c];
        zr[c * 4 + 0] = v.x;
        zr[c * 4 + 1] = v.y;
        zr[c * 4 + 2] = v.z;
        zr[c * 4 + 3] = v.w;
    }

    // argmin_k ( ||W_k||^2 - 2 <z, W_k> )   (||z||^2 is constant in k)
    float best = INFINITY;
    int   bidx = 0;
    #pragma unroll 2
    for (int k = 0; k < KK; ++k) {
        const float* wr = Ws + (size_t)k * DD;   // wave-uniform address -> s_load
        float dot = 0.0f;
        #pragma unroll
        for (int d = 0; d < DD; ++d) dot = fmaf(wr[d], zr[d], dot);
        const float m = fmaf(dot, -2.0f, lds_w2[k]);  // uniform LDS broadcast
        if (m < best) { best = m; bidx = k; }         // strict < : first-index ties
    }

    // zq = W[s, bidx]; write out and accumulate sum((zq - z)^2)
    const float* wq = Ws + (size_t)bidx * DD;        // divergent -> vector loads (L2 hit)
    float* op = out + (size_t)n * (SS * DD) + (size_t)s * DD;
    float sq = 0.0f;
    #pragma unroll
    for (int c = 0; c < DD / 4; ++c) {
        float4 wv = reinterpret_cast<const float4*>(wq)[c];
        const float d0 = wv.x - zr[c * 4 + 0];
        const float d1 = wv.y - zr[c * 4 + 1];
        const float d2 = wv.z - zr[c * 4 + 2];
        const float d3 = wv.w - zr[c * 4 + 3];
        sq = fmaf(d0, d0, sq);
        sq = fmaf(d1, d1, sq);
        sq = fmaf(d2, d2, sq);
        sq = fmaf(d3, d3, sq);
        reinterpret_cast<float4*>(op)[c] = wv;
    }

    // wave (64-lane) shuffle reduction, then block reduction via LDS
    #pragma unroll
    for (int off = 32; off > 0; off >>= 1) sq += __shfl_down(sq, off, 64);
    const int lane = tid & 63;
    const int wv_id = tid >> 6;
    if (lane == 0) lds_red[wv_id] = sq;
    __syncthreads();
    if (tid == 0) {
        const float tot = lds_red[0] + lds_red[1] + lds_red[2] + lds_red[3];
        atomicAdd(out + OUT_ELEMS, tot * LOSS_SCALE);
    }
}

extern "C" void kernel_launch(void* const* d_in, const int* in_sizes, int n_in,
                              void* d_out, int out_size, void* d_ws, size_t ws_size,
                              hipStream_t stream) {
    const float* z = (const float*)d_in[0];   // (8192, 1024) fp32
    const float* W = (const float*)d_in[1];   // (32, 1024, 32) fp32
    float* out = (float*)d_out;               // 8388608 zq_st + 1 loss

    vq_zero_loss<<<1, 1, 0, stream>>>(out);
    // 1024 blocks: blockIdx&31 = s, blockIdx>>5 = n-tile of 256
    vq_main<<<dim3((NN / 256) * SS), dim3(256), 0, stream>>>(z, W, out);
}

// Round 2
// 253.235 us; speedup vs baseline: 1.6468x; 1.6468x over previous
//
#include <hip/hip_runtime.h>
#include <math.h>

// Problem constants (fixed by reference setup_inputs)
#define NN 8192
#define SS 32
#define DD 32
#define KK 1024
#define OUT_ELEMS ((size_t)NN * SS * DD)   // 8388608; loss scalar at out[OUT_ELEMS]

// loss = S * (1 + BETA) * sum_sq / (N*S*D)
#define LOSS_SCALE (32.0f * 1.001f / 8388608.0f)

typedef _Float16 half8 __attribute__((ext_vector_type(8)));
typedef float   floatx4 __attribute__((ext_vector_type(4)));

// Workspace layout (d_ws):
//   wh : S*K*D f16   @ 0        (2 MB)  hi split of W
//   wl : S*K*D f16   @ 2 MB     (2 MB)  lo split of W
//   w2 : S*K   fp32  @ 4 MB     (128 KB) ||W_k||^2

// One thread per (s,k) codeword row: split to f16 hi/lo, compute ||W||^2.
__global__ __launch_bounds__(256) void vq_prep(const float* __restrict__ W,
                                               _Float16* __restrict__ wh,
                                               _Float16* __restrict__ wl,
                                               float* __restrict__ w2,
                                               float* __restrict__ out) {
    const int t = blockIdx.x * 256 + threadIdx.x;   // 0 .. S*K-1
    const float* wr = W + (size_t)t * DD;
    float acc = 0.0f;
    half8 hv[4], lv[4];
    #pragma unroll
    for (int d = 0; d < DD; ++d) {
        const float v = wr[d];
        acc = fmaf(v, v, acc);
        const _Float16 h = (_Float16)v;
        hv[d >> 3][d & 7] = h;
        lv[d >> 3][d & 7] = (_Float16)(v - (float)h);
    }
    half8* who = (half8*)(wh + (size_t)t * DD);
    half8* wlo = (half8*)(wl + (size_t)t * DD);
    #pragma unroll
    for (int c = 0; c < 4; ++c) { who[c] = hv[c]; wlo[c] = lv[c]; }
    w2[t] = acc;
    if (t == 0) out[OUT_ELEMS] = 0.0f;   // zero the loss accumulator
}

// Block = 256 thr = 4 waves; each wave owns 32 n-rows (2 MFMA rowgroups) for
// one s, loops over all 64 k-tiles of 16. Score = ||W_k||^2 - 2<z,W_k> via
// 3-term f16-split MFMA with w2 folded into the accumulator init.
__global__ __launch_bounds__(256, 4) void vq_mfma(const float* __restrict__ z,
                                                  const float* __restrict__ W,
                                                  const _Float16* __restrict__ wh,
                                                  const _Float16* __restrict__ wl,
                                                  const float* __restrict__ w2,
                                                  float* __restrict__ out) {
    __shared__ float lds_w2[KK];
    __shared__ int   lds_idx[4][32];

    const int s     = blockIdx.x & (SS - 1);
    const int n0b   = (blockIdx.x >> 5) * 128;
    const int tid   = threadIdx.x;
    const int wv    = tid >> 6;
    const int lane  = tid & 63;
    const int col   = lane & 15;
    const int quad  = lane >> 4;

    // Stage ||W[s,:]||^2 into LDS (4 KB)
    const float* w2s = w2 + (size_t)s * KK;
    #pragma unroll
    for (int j = 0; j < 4; ++j) lds_w2[tid + j * 256] = w2s[tid + j * 256];
    __syncthreads();

    const int n0w = n0b + wv * 32;

    // A-fragments: (-2*z) split into f16 hi/lo. A[m=lane&15][d=quad*8+j].
    half8 zh[2], zl[2];
    #pragma unroll
    for (int g = 0; g < 2; ++g) {
        const float* zp = z + (size_t)(n0w + g * 16 + col) * (SS * DD) + s * DD + quad * 8;
        #pragma unroll
        for (int j = 0; j < 8; ++j) {
            const float v = -2.0f * zp[j];
            const _Float16 h = (_Float16)v;
            zh[g][j] = h;
            zl[g][j] = (_Float16)(v - (float)h);
        }
    }

    // B-fragment base: B[d][kcol] = W[kcol][d] -> 8 contiguous f16 per lane.
    const _Float16* whs = wh + ((size_t)s * KK + col) * DD + quad * 8;
    const _Float16* wls = wl + ((size_t)s * KK + col) * DD + quad * 8;

    floatx4 best0 = {INFINITY, INFINITY, INFINITY, INFINITY};
    floatx4 best1 = best0;
    int bi0[4] = {0, 0, 0, 0}, bi1[4] = {0, 0, 0, 0};

    for (int t = 0; t < KK / 16; ++t) {
        const half8 bh = *(const half8*)(whs + (size_t)t * 16 * DD);
        const half8 bl = *(const half8*)(wls + (size_t)t * 16 * DD);
        const float wv2 = lds_w2[t * 16 + col];          // uniform-per-col broadcast
        floatx4 acc0 = {wv2, wv2, wv2, wv2};
        floatx4 acc1 = acc0;
        acc0 = __builtin_amdgcn_mfma_f32_16x16x32_f16(zh[0], bh, acc0, 0, 0, 0);
        acc1 = __builtin_amdgcn_mfma_f32_16x16x32_f16(zh[1], bh, acc1, 0, 0, 0);
        acc0 = __builtin_amdgcn_mfma_f32_16x16x32_f16(zl[0], bh, acc0, 0, 0, 0);
        acc1 = __builtin_amdgcn_mfma_f32_16x16x32_f16(zl[1], bh, acc1, 0, 0, 0);
        acc0 = __builtin_amdgcn_mfma_f32_16x16x32_f16(zh[0], bl, acc0, 0, 0, 0);
        acc1 = __builtin_amdgcn_mfma_f32_16x16x32_f16(zh[1], bl, acc1, 0, 0, 0);
        #pragma unroll
        for (int i = 0; i < 4; ++i) {
            if (acc0[i] < best0[i]) { best0[i] = acc0[i]; bi0[i] = t; }  // strict <: first-index
            if (acc1[i] < best1[i]) { best1[i] = acc1[i]; bi1[i] = t; }
        }
    }

    // Cross-lane argmin over the 16 k-columns (lanes sharing a quad group).
    // Tie-break: lower k wins (np.argmin first-index rule).
    #pragma unroll
    for (int g = 0; g < 2; ++g) {
        #pragma unroll
        for (int i = 0; i < 4; ++i) {
            float v = g ? best1[i] : best0[i];
            int   k = (g ? bi1[i] : bi0[i]) * 16 + col;
            #pragma unroll
            for (int m = 1; m < 16; m <<= 1) {
                const float vo = __shfl_xor(v, m, 64);
                const int   ko = __shfl_xor(k, m, 64);
                if (vo < v || (vo == v && ko < k)) { v = vo; k = ko; }
            }
            if (col == 0) lds_idx[wv][g * 16 + quad * 4 + i] = k;  // row = g*16+quad*4+i
        }
    }
    __syncthreads();

    // Epilogue: zq = fp32 W[s, k*]; write out + accumulate sum((zq-z)^2).
    // Lane -> (row = lane&31, d-half = (lane>>5)*16): 16 floats each.
    const int r  = lane & 31;
    const int dh = (lane >> 5) * 16;
    const int krow = lds_idx[wv][r];
    const float* wsrc = W + ((size_t)s * KK + krow) * DD + dh;
    const size_t zoff = (size_t)(n0w + r) * (SS * DD) + s * DD + dh;
    const float* zsrc = z + zoff;
    float* od = out + zoff;
    float sq = 0.0f;
    #pragma unroll
    for (int c = 0; c < 4; ++c) {
        const float4 wq = ((const float4*)wsrc)[c];
        const float4 zv = ((const float4*)zsrc)[c];
        const float d0 = wq.x - zv.x, d1 = wq.y - zv.y;
        const float d2 = wq.z - zv.z, d3 = wq.w - zv.w;
        sq = fmaf(d0, d0, sq); sq = fmaf(d1, d1, sq);
        sq = fmaf(d2, d2, sq); sq = fmaf(d3, d3, sq);
        ((float4*)od)[c] = wq;
    }
    #pragma unroll
    for (int off = 32; off > 0; off >>= 1) sq += __shfl_down(sq, off, 64);
    if (lane == 0) atomicAdd(out + OUT_ELEMS, sq * LOSS_SCALE);
}

extern "C" void kernel_launch(void* const* d_in, const int* in_sizes, int n_in,
                              void* d_out, int out_size, void* d_ws, size_t ws_size,
                              hipStream_t stream) {
    const float* z = (const float*)d_in[0];   // (8192, 1024) fp32
    const float* W = (const float*)d_in[1];   // (32, 1024, 32) fp32
    float* out = (float*)d_out;               // 8388608 zq_st + 1 loss

    _Float16* wh = (_Float16*)d_ws;
    _Float16* wl = wh + (size_t)SS * KK * DD;
    float*    w2 = (float*)(wl + (size_t)SS * KK * DD);

    vq_prep<<<dim3((SS * KK) / 256), dim3(256), 0, stream>>>(W, wh, wl, w2, out);
    // 2048 blocks: blockIdx&31 = s, blockIdx>>5 = 128-row n-tile
    vq_mfma<<<dim3((NN / 128) * SS), dim3(256), 0, stream>>>(z, W, wh, wl, w2, out);
}

// Round 3
// 176.911 us; speedup vs baseline: 2.3572x; 1.4314x over previous
//
#include <hip/hip_runtime.h>
#include <math.h>

// Problem constants (fixed by reference setup_inputs)
#define NN 8192
#define SS 32
#define DD 32
#define KK 1024
#define OUT_ELEMS ((size_t)NN * SS * DD)   // 8388608; loss scalar at out[OUT_ELEMS]

// loss = S * (1 + BETA) * sum_sq / (N*S*D)
#define LOSS_SCALE (32.0f * 1.001f / 8388608.0f)

typedef _Float16 half8 __attribute__((ext_vector_type(8)));
typedef float   floatx4 __attribute__((ext_vector_type(4)));

// Workspace layout (d_ws):
//   wh : S*K*D f16   @ 0        (2 MB)  hi split of W
//   wl : S*K*D f16   @ 2 MB     (2 MB)  lo split of W
//   w2 : S*K   fp32  @ 4 MB     (128 KB) ||W_k||^2
// NOTE: vq_mfma's pipelined B-prefetch reads up to 1 KB past the end of the
// current s-slice on the last k-tile; that lands in the adjacent ws region
// (valid memory) and the value is never consumed.

// 4 lanes per (s,k) codeword row: float4 loads, split to f16 hi/lo,
// 4-lane shuffle reduce for ||W||^2.
__global__ __launch_bounds__(256) void vq_prep(const float* __restrict__ W,
                                               _Float16* __restrict__ wh,
                                               _Float16* __restrict__ wl,
                                               float* __restrict__ w2,
                                               float* __restrict__ out) {
    const int g    = blockIdx.x * 256 + threadIdx.x;   // 0 .. S*K*4-1
    const int row  = g >> 2;
    const int part = g & 3;                            // 8 floats each
    const float* wr = W + (size_t)row * DD + part * 8;
    const float4 a = ((const float4*)wr)[0];
    const float4 b = ((const float4*)wr)[1];
    float ps = 0.0f;
    ps = fmaf(a.x, a.x, ps); ps = fmaf(a.y, a.y, ps);
    ps = fmaf(a.z, a.z, ps); ps = fmaf(a.w, a.w, ps);
    ps = fmaf(b.x, b.x, ps); ps = fmaf(b.y, b.y, ps);
    ps = fmaf(b.z, b.z, ps); ps = fmaf(b.w, b.w, ps);
    ps += __shfl_xor(ps, 1, 64);
    ps += __shfl_xor(ps, 2, 64);
    if (part == 0) w2[row] = ps;

    const float src[8] = {a.x, a.y, a.z, a.w, b.x, b.y, b.z, b.w};
    half8 h, l;
    #pragma unroll
    for (int j = 0; j < 8; ++j) {
        const _Float16 hv = (_Float16)src[j];
        h[j] = hv;
        l[j] = (_Float16)(src[j] - (float)hv);
    }
    *(half8*)(wh + (size_t)row * DD + part * 8) = h;
    *(half8*)(wl + (size_t)row * DD + part * 8) = l;
    if (g == 0) out[OUT_ELEMS] = 0.0f;   // zero the loss accumulator
}

#define RG 4   // 16-row MFMA rowgroups per wave -> 64 n-rows/wave, 256/block

// Block = 4 waves, one s per block, 256 n-rows. Score(n,k) = ||W_k||^2 -
// 2<z_n,W_k> via 3-term f16-split MFMA (w2 folded into acc init), software-
// pipelined B prefetch, per-slot argmin, cross-lane combine, fp32-W epilogue.
__global__ __launch_bounds__(256, 4) void vq_mfma(const float* __restrict__ z,
                                                  const float* __restrict__ W,
                                                  const _Float16* __restrict__ wh,
                                                  const _Float16* __restrict__ wl,
                                                  const float* __restrict__ w2,
                                                  float* __restrict__ out) {
    __shared__ float lds_w2[KK + 16];   // +16: tail prefetch pad (unused value)
    __shared__ int   lds_idx[4][64];

    const int s    = blockIdx.x & (SS - 1);   // same-XCD blocks share few s
    const int n0b  = (blockIdx.x >> 5) * 256;
    const int tid  = threadIdx.x;
    const int wv   = tid >> 6;
    const int lane = tid & 63;
    const int col  = lane & 15;
    const int quad = lane >> 4;

    const float* w2s = w2 + (size_t)s * KK;
    #pragma unroll
    for (int j = 0; j < 4; ++j) lds_w2[tid + j * 256] = w2s[tid + j * 256];
    __syncthreads();

    const int n0w = n0b + wv * 64;

    // A-fragments: (-2*z) split into f16 hi/lo. A[m=col][d=quad*8+j].
    half8 zh[RG], zl[RG];
    #pragma unroll
    for (int rg = 0; rg < RG; ++rg) {
        const float* zp = z + (size_t)(n0w + rg * 16 + col) * (SS * DD) + s * DD + quad * 8;
        const float4 va = ((const float4*)zp)[0];
        const float4 vb = ((const float4*)zp)[1];
        const float src[8] = {va.x, va.y, va.z, va.w, vb.x, vb.y, vb.z, vb.w};
        #pragma unroll
        for (int j = 0; j < 8; ++j) {
            const float v = -2.0f * src[j];
            const _Float16 h = (_Float16)v;
            zh[rg][j] = h;
            zl[rg][j] = (_Float16)(v - (float)h);
        }
    }

    // B-fragment base: lane reads wh[s][t*16+col][quad*8 .. +7] (16 B).
    const _Float16* whs = wh + ((size_t)s * KK + col) * DD + quad * 8;
    const _Float16* wls = wl + ((size_t)s * KK + col) * DD + quad * 8;

    floatx4 best[RG];
    int bi[RG][4];
    #pragma unroll
    for (int rg = 0; rg < RG; ++rg) {
        best[rg] = (floatx4){INFINITY, INFINITY, INFINITY, INFINITY};
        bi[rg][0] = bi[rg][1] = bi[rg][2] = bi[rg][3] = 0;
    }

    // Software pipeline: B/w2 for tile t+1 in flight during tile t's compute.
    half8 bh = *(const half8*)(whs);
    half8 bl = *(const half8*)(wls);
    float wv2 = lds_w2[col];

    for (int t = 0; t < KK / 16; ++t) {
        // prefetch t+1 (tail reads pad/adjacent ws; value unused)
        const half8 bh_n = *(const half8*)(whs + (size_t)(t + 1) * 16 * DD);
        const half8 bl_n = *(const half8*)(wls + (size_t)(t + 1) * 16 * DD);
        const float wv2_n = lds_w2[(t + 1) * 16 + col];

        #pragma unroll
        for (int rg = 0; rg < RG; ++rg) {
            floatx4 acc = {wv2, wv2, wv2, wv2};
            acc = __builtin_amdgcn_mfma_f32_16x16x32_f16(zh[rg], bh, acc, 0, 0, 0);
            acc = __builtin_amdgcn_mfma_f32_16x16x32_f16(zl[rg], bh, acc, 0, 0, 0);
            acc = __builtin_amdgcn_mfma_f32_16x16x32_f16(zh[rg], bl, acc, 0, 0, 0);
            #pragma unroll
            for (int i = 0; i < 4; ++i) {
                if (acc[i] < best[rg][i]) { best[rg][i] = acc[i]; bi[rg][i] = t; }  // strict <
            }
        }
        bh = bh_n; bl = bl_n; wv2 = wv2_n;
    }

    // Cross-lane argmin over the 16 k-columns; lower k wins ties (np rule).
    #pragma unroll
    for (int rg = 0; rg < RG; ++rg) {
        #pragma unroll
        for (int i = 0; i < 4; ++i) {
            float v = best[rg][i];
            int   k = bi[rg][i] * 16 + col;
            #pragma unroll
            for (int m = 1; m < 16; m <<= 1) {
                const float vo = __shfl_xor(v, m, 64);
                const int   ko = __shfl_xor(k, m, 64);
                if (vo < v || (vo == v && ko < k)) { v = vo; k = ko; }
            }
            if (col == 0) lds_idx[wv][rg * 16 + quad * 4 + i] = k;  // row-in-wave
        }
    }
    __syncthreads();

    // Epilogue: one lane per n-row. zq = fp32 W[s,k*]; write + loss partial.
    const int krow = lds_idx[wv][lane];
    const float* wsrc = W + ((size_t)s * KK + krow) * DD;
    const size_t zoff = (size_t)(n0w + lane) * (SS * DD) + s * DD;
    const float* zsrc = z + zoff;
    float* od = out + zoff;
    float sq = 0.0f;
    #pragma unroll
    for (int c = 0; c < 8; ++c) {
        const float4 wq = ((const float4*)wsrc)[c];
        const float4 zv = ((const float4*)zsrc)[c];
        const float d0 = wq.x - zv.x, d1 = wq.y - zv.y;
        const float d2 = wq.z - zv.z, d3 = wq.w - zv.w;
        sq = fmaf(d0, d0, sq); sq = fmaf(d1, d1, sq);
        sq = fmaf(d2, d2, sq); sq = fmaf(d3, d3, sq);
        ((float4*)od)[c] = wq;
    }
    #pragma unroll
    for (int off = 32; off > 0; off >>= 1) sq += __shfl_down(sq, off, 64);
    if (lane == 0) atomicAdd(out + OUT_ELEMS, sq * LOSS_SCALE);
}

extern "C" void kernel_launch(void* const* d_in, const int* in_sizes, int n_in,
                              void* d_out, int out_size, void* d_ws, size_t ws_size,
                              hipStream_t stream) {
    const float* z = (const float*)d_in[0];   // (8192, 1024) fp32
    const float* W = (const float*)d_in[1];   // (32, 1024, 32) fp32
    float* out = (float*)d_out;               // 8388608 zq_st + 1 loss

    _Float16* wh = (_Float16*)d_ws;
    _Float16* wl = wh + (size_t)SS * KK * DD;
    float*    w2 = (float*)(wl + (size_t)SS * KK * DD);

    vq_prep<<<dim3((SS * KK * 4) / 256), dim3(256), 0, stream>>>(W, wh, wl, w2, out);
    // 1024 blocks: blockIdx&31 = s, blockIdx>>5 = 256-row n-tile
    vq_mfma<<<dim3((NN / 256) * SS), dim3(256), 0, stream>>>(z, W, wh, wl, w2, out);
}

// Round 4
// 174.536 us; speedup vs baseline: 2.3893x; 1.0136x over previous
//
#include <hip/hip_runtime.h>
#include <math.h>

// Problem constants (fixed by reference setup_inputs)
#define NN 8192
#define SS 32
#define DD 32
#define KK 1024
#define OUT_ELEMS ((size_t)NN * SS * DD)   // 8388608; loss scalar at out[OUT_ELEMS]

// loss = S * (1 + BETA) * sum_sq / (N*S*D)
#define LOSS_SCALE (32.0f * 1.001f / 8388608.0f)

typedef _Float16 half8 __attribute__((ext_vector_type(8)));
typedef float   floatx4 __attribute__((ext_vector_type(4)));

#define CH_TILES 4                    // k-tiles of 16 per chunk
#define CHUNK_K  (CH_TILES * 16)      // 64 codewords per chunk
#define NCHUNK   (KK / CHUNK_K)       // 16 chunks

// One fused kernel. Block = 4 waves = 256 thr, one s per block, 256 n-rows.
// K-loop: per chunk, 256 threads cooperatively load fp32 W, split to f16
// hi/lo into LDS (fragment-order, conflict-free), compute ||W||^2; then each
// wave runs 4 tiles x 3 split-MFMAs with per-slot argmin. Double-buffered.
__global__ __launch_bounds__(256, 2) void vq_fused(const float* __restrict__ z,
                                                   const float* __restrict__ W,
                                                   float* __restrict__ out) {
    // Fragment-order staging: buf[b][tile][lane][8 f16] -> lane reads its own
    // 16 B (ds_read_b128, contiguous per lane = conflict-free); writer thread
    // t writes slot t (same pattern) so ds_write_b128 is conflict-free too.
    __shared__ _Float16 bufH[2][CH_TILES][64][8];   // 8 KB
    __shared__ _Float16 bufL[2][CH_TILES][64][8];   // 8 KB
    __shared__ float    w2b[2][CHUNK_K];            // 512 B
    __shared__ int      lds_idx[4][64];             // 1 KB

    const int s    = blockIdx.x & (SS - 1);
    const int n0b  = (blockIdx.x >> 5) * 256;
    const int tid  = threadIdx.x;
    const int wv   = tid >> 6;
    const int lane = tid & 63;
    const int col  = lane & 15;
    const int quad = lane >> 4;

    const float* __restrict__ Ws = W + (size_t)s * KK * DD;
    const int n0w = n0b + wv * 64;

    // ---- A-fragments: (-2*z) split into f16 hi/lo. A[m=col][d=quad*8+j]. ----
    half8 zh[4], zl[4];
    #pragma unroll
    for (int rg = 0; rg < 4; ++rg) {
        const float* zp = z + (size_t)(n0w + rg * 16 + col) * (SS * DD) + s * DD + quad * 8;
        const float4 va = ((const float4*)zp)[0];
        const float4 vb = ((const float4*)zp)[1];
        const float src[8] = {va.x, va.y, va.z, va.w, vb.x, vb.y, vb.z, vb.w};
        #pragma unroll
        for (int j = 0; j < 8; ++j) {
            const float v = -2.0f * src[j];
            const _Float16 h = (_Float16)v;
            zh[rg][j] = h;
            zl[rg][j] = (_Float16)(v - (float)h);
        }
    }

    // Staging source for this thread: k-row = (chunk*4 + wv)*16 + col,
    // d-range = quad*8 .. +8  (wave covers a 16-row x 128 B contiguous slab).
    const float* __restrict__ stg = Ws + ((size_t)(wv * 16 + col)) * DD + quad * 8;

    floatx4 best[4];
    int bi[4][4];
    #pragma unroll
    for (int rg = 0; rg < 4; ++rg) {
        best[rg] = (floatx4){INFINITY, INFINITY, INFINITY, INFINITY};
        bi[rg][0] = bi[rg][1] = bi[rg][2] = bi[rg][3] = 0;
    }

    // ---- prologue: stage chunk 0 ----
    float4 pa = ((const float4*)stg)[0];
    float4 pb = ((const float4*)stg)[1];
    {
        const float src[8] = {pa.x, pa.y, pa.z, pa.w, pb.x, pb.y, pb.z, pb.w};
        half8 h8, l8; float ps = 0.0f;
        #pragma unroll
        for (int j = 0; j < 8; ++j) {
            const float v = src[j];
            ps = fmaf(v, v, ps);
            const _Float16 h = (_Float16)v;
            h8[j] = h;
            l8[j] = (_Float16)(v - (float)h);
        }
        ps += __shfl_xor(ps, 16, 64);
        ps += __shfl_xor(ps, 32, 64);
        *(half8*)&bufH[0][wv][lane][0] = h8;
        *(half8*)&bufL[0][wv][lane][0] = l8;
        if (quad == 0) w2b[0][wv * 16 + col] = ps;
    }
    __syncthreads();

    // ---- main K loop, double-buffered ----
    for (int c = 0; c < NCHUNK; ++c) {
        const int b = c & 1;
        // issue next chunk's global loads before compute (L2 latency cover)
        if (c + 1 < NCHUNK) {
            const float* nsrc = stg + (size_t)(c + 1) * CHUNK_K * DD;
            pa = ((const float4*)nsrc)[0];
            pb = ((const float4*)nsrc)[1];
        }

        #pragma unroll
        for (int tt = 0; tt < CH_TILES; ++tt) {
            const half8 bh = *(const half8*)&bufH[b][tt][lane][0];
            const half8 bl = *(const half8*)&bufL[b][tt][lane][0];
            const float wv2 = w2b[b][tt * 16 + col];
            const floatx4 c0 = {wv2, wv2, wv2, wv2};     // shared across rowgroups
            const int tk = c * CH_TILES + tt;
            #pragma unroll
            for (int rg = 0; rg < 4; ++rg) {
                floatx4 acc = __builtin_amdgcn_mfma_f32_16x16x32_f16(zh[rg], bh, c0, 0, 0, 0);
                acc = __builtin_amdgcn_mfma_f32_16x16x32_f16(zl[rg], bh, acc, 0, 0, 0);
                acc = __builtin_amdgcn_mfma_f32_16x16x32_f16(zh[rg], bl, acc, 0, 0, 0);
                #pragma unroll
                for (int i = 0; i < 4; ++i) {
                    if (acc[i] < best[rg][i]) { best[rg][i] = acc[i]; bi[rg][i] = tk; }  // strict <
                }
            }
        }

        if (c + 1 < NCHUNK) {
            const float src[8] = {pa.x, pa.y, pa.z, pa.w, pb.x, pb.y, pb.z, pb.w};
            half8 h8, l8; float ps = 0.0f;
            #pragma unroll
            for (int j = 0; j < 8; ++j) {
                const float v = src[j];
                ps = fmaf(v, v, ps);
                const _Float16 h = (_Float16)v;
                h8[j] = h;
                l8[j] = (_Float16)(v - (float)h);
            }
            ps += __shfl_xor(ps, 16, 64);
            ps += __shfl_xor(ps, 32, 64);
            const int nb = (c + 1) & 1;
            *(half8*)&bufH[nb][wv][lane][0] = h8;
            *(half8*)&bufL[nb][wv][lane][0] = l8;
            if (quad == 0) w2b[nb][wv * 16 + col] = ps;
            __syncthreads();
        }
    }

    // ---- cross-lane argmin over the 16 k-columns; lower k wins ties ----
    #pragma unroll
    for (int rg = 0; rg < 4; ++rg) {
        #pragma unroll
        for (int i = 0; i < 4; ++i) {
            float v = best[rg][i];
            int   k = bi[rg][i] * 16 + col;
            #pragma unroll
            for (int m = 1; m < 16; m <<= 1) {
                const float vo = __shfl_xor(v, m, 64);
                const int   ko = __shfl_xor(k, m, 64);
                if (vo < v || (vo == v && ko < k)) { v = vo; k = ko; }
            }
            if (col == 0) lds_idx[wv][rg * 16 + quad * 4 + i] = k;  // row-in-wave
        }
    }
    __syncthreads();

    // ---- epilogue: one lane per n-row; zq = fp32 W[s,k*]; write + loss ----
    const int krow = lds_idx[wv][lane];
    const float* wsrc = Ws + (size_t)krow * DD;
    const size_t zoff = (size_t)(n0w + lane) * (SS * DD) + s * DD;
    const float* zsrc = z + zoff;
    float* od = out + zoff;
    float sq = 0.0f;
    #pragma unroll
    for (int cc = 0; cc < 8; ++cc) {
        const float4 wq = ((const float4*)wsrc)[cc];
        const float4 zv = ((const float4*)zsrc)[cc];
        const float d0 = wq.x - zv.x, d1 = wq.y - zv.y;
        const float d2 = wq.z - zv.z, d3 = wq.w - zv.w;
        sq = fmaf(d0, d0, sq); sq = fmaf(d1, d1, sq);
        sq = fmaf(d2, d2, sq); sq = fmaf(d3, d3, sq);
        ((float4*)od)[cc] = wq;
    }
    #pragma unroll
    for (int off = 32; off > 0; off >>= 1) sq += __shfl_down(sq, off, 64);
    if (lane == 0) atomicAdd(out + OUT_ELEMS, sq * LOSS_SCALE);
}

extern "C" void kernel_launch(void* const* d_in, const int* in_sizes, int n_in,
                              void* d_out, int out_size, void* d_ws, size_t ws_size,
                              hipStream_t stream) {
    const float* z = (const float*)d_in[0];   // (8192, 1024) fp32
    const float* W = (const float*)d_in[1];   // (32, 1024, 32) fp32
    float* out = (float*)d_out;               // 8388608 zq_st + 1 loss

    // zero the loss accumulator (memset node is graph-capture-safe)
    hipMemsetAsync((char*)out + OUT_ELEMS * sizeof(float), 0, sizeof(float), stream);
    // 1024 blocks: blockIdx&31 = s, blockIdx>>5 = 256-row n-tile
    vq_fused<<<dim3((NN / 256) * SS), dim3(256), 0, stream>>>(z, W, out);
}